// Round 8
// baseline (133.759 us; speedup 1.0000x reference)
//
#include <hip/hip_runtime.h>
#include <hip/hip_bf16.h>

// LIF: V = V + (I - V)/tau; spike = V >= 1.0; V = spike ? 0 : V
// d_out = [spike_trace (0/1 f32) | voltage_trace (f32)], each T*B*N.
//
// R7: engineered L3 residency. Input = 268 MB vs 256 MB Infinity Cache ->
// a fully-cached stream near-thrashes. Split by timestep:
//   t in [0, 448):  cached loads  (224 MB working set, fits L3 with margin;
//                   identical access every graph replay -> RRIP converges
//                   to residency)
//   t in [448,512): nontemporal loads (32 MB, never pollutes the resident set)
// Stores remain nontemporal (537 MB write stream must not evict reads).
// Structure otherwise = R6 winner: scalar dword, U=8 load batch, 2048 waves.

#define LIF_T 512
#define T_SPLIT 448
#define V_TH 1.0f
#define TAU 20.0f
#define U 8

__global__ __launch_bounds__(256) void lif_kernel(const float* __restrict__ in,
                                                  float* __restrict__ spikes,
                                                  float* __restrict__ volts,
                                                  int BN) {
    const int i = blockIdx.x * blockDim.x + threadIdx.x;
    if (i >= BN) return;

    float V = 0.0f;
    size_t off = (size_t)i;
    const size_t stride = (size_t)BN;

    // Phase 1: t in [0, T_SPLIT) — cached loads (L3-resident set).
    for (int t = 0; t < T_SPLIT; t += U) {
        float Iv[U];
        #pragma unroll
        for (int u = 0; u < U; ++u)
            Iv[u] = in[off + (size_t)u * stride];

        #pragma unroll
        for (int u = 0; u < U; ++u) {
            const size_t o = off + (size_t)u * stride;
            // EXACT reference op order in f32: sub, IEEE div by 20.0f, add.
            V = V + (Iv[u] - V) / TAU;
            const bool s = (V >= V_TH);
            __builtin_nontemporal_store(s ? 1.0f : 0.0f, &spikes[o]);
            V = s ? 0.0f : V;
            __builtin_nontemporal_store(V, &volts[o]);
        }
        off += (size_t)U * stride;
    }

    // Phase 2: t in [T_SPLIT, LIF_T) — nontemporal loads (no L3 pollution).
    for (int t = T_SPLIT; t < LIF_T; t += U) {
        float Iv[U];
        #pragma unroll
        for (int u = 0; u < U; ++u)
            Iv[u] = __builtin_nontemporal_load(&in[off + (size_t)u * stride]);

        #pragma unroll
        for (int u = 0; u < U; ++u) {
            const size_t o = off + (size_t)u * stride;
            V = V + (Iv[u] - V) / TAU;
            const bool s = (V >= V_TH);
            __builtin_nontemporal_store(s ? 1.0f : 0.0f, &spikes[o]);
            V = s ? 0.0f : V;
            __builtin_nontemporal_store(V, &volts[o]);
        }
        off += (size_t)U * stride;
    }
}

extern "C" void kernel_launch(void* const* d_in, const int* in_sizes, int n_in,
                              void* d_out, int out_size, void* d_ws, size_t ws_size,
                              hipStream_t stream) {
    const float* in = (const float*)d_in[0];
    float* out = (float*)d_out;

    const int total = in_sizes[0];          // T*B*N
    const int BN = total / LIF_T;           // 131072

    float* spikes = out;                     // first T*B*N floats
    float* volts  = out + (size_t)total;     // second T*B*N floats

    const int block = 256;
    const int grid = (BN + block - 1) / block;   // 512 blocks
    lif_kernel<<<grid, block, 0, stream>>>(in, spikes, volts, BN);
}

// Round 9
// 128.744 us; speedup vs baseline: 1.0389x; 1.0389x over previous
//
#include <hip/hip_runtime.h>
#include <hip/hip_bf16.h>

// LIF: V = V + (I - V)/tau; spike = V >= 1.0; V = spike ? 0 : V
// d_out = [spike_trace (0/1 f32) | voltage_trace (f32)], each T*B*N.
//
// FINAL (R6 winner, 125.3 us = 6.42 TB/s effective on 805 MB):
// - 1 thread/neuron (B*N = 131072 = 2048 waves, 2/SIMD), T=512 inner loop.
// - U=8 batched CACHED loads: plain loads beat nontemporal loads everywhere
//   (nt load path measured slower: R1 146us vs R6 125us; R7 nt-tail 134us).
// - Nontemporal STORES: 537 MB write-once stream, keep it out of L2/L3 so
//   the 268 MB read stream gets the cache.
// - Scalar dword beats float4 (R3: waves/4 -> 155us). Compiler-scheduled
//   batch beats explicit SW pipeline (R4: 171us) and U=16 (R5: 175us).
// - EXACT reference op order in f32 (sub, IEEE div by 20.0f, add) so spike
//   decisions match the JAX reference bit-for-bit.

#define LIF_T 512
#define V_TH 1.0f
#define TAU 20.0f
#define U 8

__global__ __launch_bounds__(256) void lif_kernel(const float* __restrict__ in,
                                                  float* __restrict__ spikes,
                                                  float* __restrict__ volts,
                                                  int BN) {
    const int i = blockIdx.x * blockDim.x + threadIdx.x;
    if (i >= BN) return;

    float V = 0.0f;
    size_t off = (size_t)i;
    const size_t stride = (size_t)BN;

    for (int t = 0; t < LIF_T; t += U) {
        // Batch-issue U independent cached loads.
        float Iv[U];
        #pragma unroll
        for (int u = 0; u < U; ++u)
            Iv[u] = in[off + (size_t)u * stride];

        // Loop-carried V chain + streaming (nt) stores.
        #pragma unroll
        for (int u = 0; u < U; ++u) {
            const size_t o = off + (size_t)u * stride;
            V = V + (Iv[u] - V) / TAU;
            const bool s = (V >= V_TH);
            __builtin_nontemporal_store(s ? 1.0f : 0.0f, &spikes[o]);
            V = s ? 0.0f : V;
            __builtin_nontemporal_store(V, &volts[o]);
        }
        off += (size_t)U * stride;
    }
}

extern "C" void kernel_launch(void* const* d_in, const int* in_sizes, int n_in,
                              void* d_out, int out_size, void* d_ws, size_t ws_size,
                              hipStream_t stream) {
    const float* in = (const float*)d_in[0];
    float* out = (float*)d_out;

    const int total = in_sizes[0];          // T*B*N
    const int BN = total / LIF_T;           // 131072

    float* spikes = out;                     // first T*B*N floats
    float* volts  = out + (size_t)total;     // second T*B*N floats

    const int block = 256;
    const int grid = (BN + block - 1) / block;   // 512 blocks
    lif_kernel<<<grid, block, 0, stream>>>(in, spikes, volts, BN);
}